// Round 19
// baseline (353.078 us; speedup 1.0000x reference)
//
#include <hip/hip_runtime.h>
#include <hip/hip_cooperative_groups.h>
#include <hip/hip_bf16.h>
#include <math.h>

#define HH 768
#define NB 8
#define LL 256
#define MM 128
#define NROW1 (NB*MM)        // 1024 dns rows
#define NROW2 (NB*LL)        // 2048 text rows
#define NROWS (NROW1+NROW2)  // 3072
#define NCB 12               // 768/64 column blocks
#define GRID 576

namespace cg = cooperative_groups;

typedef __attribute__((ext_vector_type(8))) short  bf16x8;
typedef __attribute__((ext_vector_type(4))) float  f32x4;

static __device__ __forceinline__ unsigned int pkbf2(float a, float b) {
    __hip_bfloat162 h = __float22bfloat162_rn(make_float2(a, b));
    unsigned int u; __builtin_memcpy(&u, &h, 4); return u;
}

static __device__ __forceinline__ float fast_tanh(float x) {
    float e = __expf(2.0f * x);
    return 1.0f - 2.0f * __builtin_amdgcn_rcpf(e + 1.0f);
}

// async global->LDS DMA, 16B per lane (r13/r14-proven).
static __device__ __forceinline__ void gload_lds16(const void* g, void* l) {
    __builtin_amdgcn_global_load_lds(
        (const __attribute__((address_space(1))) unsigned int*)g,
        (__attribute__((address_space(3))) unsigned int*)l, 16, 0, 0);
}

// ---------------------------------------------------------------------------
// Cooperative fusion of the three proven phases (r14 bodies verbatim).
// r8's failure was __launch_bounds__(256,3) -> VGPR=32 -> total spill; this
// version uses the DEFAULT register budget (expect VGPR ~100-160, no spill).
// Co-residency: 48 KB LDS -> 3 blocks/CU -> 768 >= 576 blocks resident.
// phase 1: prep (grid-stride 6, exact cover)   [r8-proven mapping]
// phase 2: score (r14: gload_lds16 + src-XOR swizzle, 3-buffer, 1 barrier,
//          counted vmcnt(4))
// phase 3: tail on blocks 0..383 (r7), LDS reused.
// Device fences around grid.sync for cross-XCD visibility (r8-validated).
// ---------------------------------------------------------------------------
__global__ __launch_bounds__(256) void fused_all(
    const float4* __restrict__ text4, const float4* __restrict__ dns4,
    const float4* __restrict__ Wd14,  const float4* __restrict__ Wt24,
    const float* __restrict__ text,   const float* __restrict__ dns,
    const float* __restrict__ wv1,    const float* __restrict__ wv2,
    unsigned short* __restrict__ Xb,  unsigned short* __restrict__ Wb,
    float* __restrict__ partial,      float* __restrict__ out)
{
    cg::grid_group grid = cg::this_grid();
    __shared__ __align__(16) unsigned short A3[3][64 * 64];   // 24 KB
    __shared__ __align__(16) unsigned short B3[3][64 * 64];   // 24 KB

    const int t = threadIdx.x;
    const int bid = blockIdx.x;

    // ---------------- phase 1: prep (verbatim r8 mapping) ----------------
    {
        int i = bid * 256 + t;
        #pragma unroll 1
        for (int it = 0; it < 6; ++it, i += GRID * 256) {   // 6*147456 = 884736
            const float4* src; uint2* dst;
            if (i < 589824) {
                dst = (uint2*)Xb + i;
                src = (i < 196608) ? (dns4 + i) : (text4 + (i - 196608));
            } else {
                dst = (uint2*)Wb + (i - 589824);
                src = (i < 737280) ? (Wd14 + (i - 589824)) : (Wt24 + (i - 737280));
            }
            float4 v = *src;
            uint2 o; o.x = pkbf2(v.x, v.y); o.y = pkbf2(v.z, v.w);
            *dst = o;
        }
    }
    __threadfence();
    grid.sync();
    __threadfence();

    // ---------------- phase 2: score (verbatim r14) ----------------
    {
        const int tile = (bid >> 3) + (bid & 7) * 72;  // 576 = 8*72, bijective
        const int rb = tile / 12, cb = tile % 12;
        const int row0 = rb * 64, col0 = cb * 64;

        const unsigned short* X = Xb + (size_t)row0 * HH;
        const unsigned short* W; const float* wv;
        if (row0 < NROW1) { W = Wb;                    wv = wv1; }
        else              { W = Wb + (size_t)HH * HH;  wv = wv2; }

        const int l  = t & 63;
        const int w  = t >> 6;
        const int wr = w * 16;
        const int lc = l & 15;

        const int roff = l >> 3;                    // 0..7
        const int gch  = ((l & 7) ^ roff) * 8;      // swizzled global k offset
        const int rA0  = w * 16 + roff;
        const unsigned short* apx = X + (size_t)rA0 * HH + gch;
        const unsigned short* bpx = W + (size_t)(col0 + rA0) * HH + gch;

        f32x4 acc[4] = {};

        auto STAGE = [&](int buf, int k0) {
            unsigned short* Abase = &A3[buf][(w * 16) * 64];
            unsigned short* Bbase = &B3[buf][(w * 16) * 64];
            gload_lds16(apx + k0,            Abase);
            gload_lds16(apx + 8 * HH + k0,   Abase + 8 * 64);
            gload_lds16(bpx + k0,            Bbase);
            gload_lds16(bpx + 8 * HH + k0,   Bbase + 8 * 64);
        };

        auto MFMA_TILE = [&](int buf) {
            #pragma unroll
            for (int kk = 0; kk < 2; ++kk) {
                const int C = kk * 4 + (l >> 4);                 // k-chunk 0..7
                const int sw = (C ^ (lc & 7)) * 8;               // swizzled chunk
                bf16x8 a = *reinterpret_cast<const bf16x8*>(&A3[buf][(wr + lc) * 64 + sw]);
                #pragma unroll
                for (int n = 0; n < 4; ++n) {
                    bf16x8 b = *reinterpret_cast<const bf16x8*>(&B3[buf][(n * 16 + lc) * 64 + sw]);
                    acc[n] = __builtin_amdgcn_mfma_f32_16x16x32_bf16(a, b, acc[n], 0, 0, 0);
                }
            }
        };

        STAGE(0, 0);
        STAGE(1, 64);

        #pragma unroll 1
        for (int k = 0; k < 12; ++k) {
            if (k < 11) asm volatile("s_waitcnt vmcnt(4)" ::: "memory");
            else        asm volatile("s_waitcnt vmcnt(0)" ::: "memory");
            __builtin_amdgcn_s_barrier();         // tile k landed in all waves
            MFMA_TILE(k % 3);
            __builtin_amdgcn_sched_barrier(0);    // pin reads before next DMAs
            if (k < 10) STAGE((k + 2) % 3, (k + 2) * 64);
        }

        float wvn[4];
        #pragma unroll
        for (int n = 0; n < 4; ++n) wvn[n] = wv[col0 + n*16 + lc];
        #pragma unroll
        for (int i = 0; i < 4; ++i) {
            float s = 0.f;
            #pragma unroll
            for (int n = 0; n < 4; ++n) s += fast_tanh(acc[n][i]) * wvn[n];
            s += __shfl_xor(s, 1);
            s += __shfl_xor(s, 2);
            s += __shfl_xor(s, 4);
            s += __shfl_xor(s, 8);
            if (lc == 0)
                partial[(size_t)(row0 + wr + (l >> 4)*4 + i) * NCB + cb] = s;
        }
    }
    __threadfence();
    grid.sync();
    __threadfence();

    // ---------------- phase 3: tail (blocks 0..383, verbatim r7) ----------
    if (bid < 384) {
        const int b = bid / 48, hc = bid % 48;
        float* fb  = (float*)&A3[0][0];        // reuse LDS: 904 floats
        float* p1s = fb;                       // 128
        float* p2s = fb + 128;                 // 256
        float* red = fb + 384;                 // 8
        float* bt  = fb + 392;                 // 256 (16B-aligned)
        float* bd  = fb + 648;                 // 256 (16B-aligned)

        if (t < 128) {
            const float* pr = partial + (size_t)(b * MM + t) * NCB;
            float s = 0.f;
            #pragma unroll
            for (int c = 0; c < NCB; ++c) s += pr[c];
            p1s[t] = s;
        }
        {
            const float* pr = partial + (size_t)(NROW1 + b * LL + t) * NCB;
            float s = 0.f;
            #pragma unroll
            for (int c = 0; c < NCB; ++c) s += pr[c];
            p2s[t] = s;
        }
        __syncthreads();

        float x1 = (t < 128) ? p1s[t] : -1e30f;
        float m1 = x1;
        #pragma unroll
        for (int d = 1; d < 64; d <<= 1) m1 = fmaxf(m1, __shfl_xor(m1, d));
        if ((t & 63) == 0) red[t >> 6] = m1;
        float x2 = p2s[t];
        float m2 = x2;
        #pragma unroll
        for (int d = 1; d < 64; d <<= 1) m2 = fmaxf(m2, __shfl_xor(m2, d));
        if ((t & 63) == 0) red[4 + (t >> 6)] = m2;
        __syncthreads();
        m1 = fmaxf(fmaxf(red[0], red[1]), fmaxf(red[2], red[3]));
        m2 = fmaxf(fmaxf(red[4], red[5]), fmaxf(red[6], red[7]));

        float e1 = (t < 128) ? __expf(x1 - m1) : 0.f;
        float e2 = __expf(x2 - m2);
        __syncthreads();
        float s1 = e1, s2 = e2;
        #pragma unroll
        for (int d = 1; d < 64; d <<= 1) { s1 += __shfl_xor(s1, d); s2 += __shfl_xor(s2, d); }
        if ((t & 63) == 0) { red[t >> 6] = s1; red[4 + (t >> 6)] = s2; }
        __syncthreads();
        s1 = red[0] + red[1] + red[2] + red[3];
        s2 = red[4] + red[5] + red[6] + red[7];
        if (t < 128) p1s[t] = e1 / s1;
        p2s[t] = e2 / s2;
        __syncthreads();

        const int hh  = hc * 16 + (t & 15);
        const int rsl = t >> 4;                      // 0..15 row-slices

        const int jr0 = rsl * 16;                    // 16 text rows per slice
        float st = 0.f;
        #pragma unroll
        for (int r = 0; r < 16; ++r)
            st = fmaf(p2s[jr0 + r], text[(size_t)(b * LL + jr0 + r) * HH + hh], st);

        const int mr0 = rsl * 8;                     // 8 dns rows per slice
        float sd = 0.f;
        #pragma unroll
        for (int r = 0; r < 8; ++r)
            sd = fmaf(p1s[mr0 + r], dns[(size_t)(b * MM + mr0 + r) * HH + hh], sd);

        bt[t] = st; bd[t] = sd;
        __syncthreads();
        if (t < 128) { bt[t] += bt[t + 128]; bd[t] += bd[t + 128]; } __syncthreads();
        if (t < 64)  { bt[t] += bt[t + 64];  bd[t] += bd[t + 64];  } __syncthreads();
        if (t < 32)  { bt[t] += bt[t + 32];  bd[t] += bd[t + 32];  } __syncthreads();
        if (t < 16)  { bt[t] += bt[t + 16];  bd[t] += bd[t + 16];  }
        __syncthreads();

        const int H4 = HH / 4;                       // 192
        const int n4out = NB * LL * H4;              // 393216
        const float4* svt4 = reinterpret_cast<const float4*>(bt);
        const float4* svd4 = reinterpret_cast<const float4*>(bd);
        float4* out4 = reinterpret_cast<float4*>(out);
        #pragma unroll
        for (int i = t; i < LL * 4; i += 256) {      // 1024 = 256 rows x 4 f4
            const int ll = i >> 2, c4 = i & 3;
            const size_t o = (size_t)(b * LL + ll) * H4 + hc * 4 + c4;
            out4[o] = svt4[c4];
            out4[n4out + o] = svd4[c4];
        }
    }
}

extern "C" void kernel_launch(void* const* d_in, const int* in_sizes, int n_in,
                              void* d_out, int out_size, void* d_ws, size_t ws_size,
                              hipStream_t stream) {
    const float* text   = (const float*)d_in[0];   // (8,256,768)
    const float* dns    = (const float*)d_in[1];   // (8,128,768)
    const float* W_d1   = (const float*)d_in[4];   // (768,768)
    const float* w_att1 = (const float*)d_in[5];   // (1536,)
    const float* W_t2   = (const float*)d_in[9];   // (768,768)
    const float* w_att2 = (const float*)d_in[10];  // (1536,)

    float* ws      = (float*)d_ws;
    float* partial = ws;                                   // 36864 f
    unsigned short* Xb = (unsigned short*)(ws + 36864);    // 2359296 bf16
    unsigned short* Wb = Xb + (size_t)NROWS * HH;          // 1179648 bf16
    float* out     = (float*)d_out;

    const float4* text4 = (const float4*)text;
    const float4* dns4  = (const float4*)dns;
    const float4* Wd14  = (const float4*)W_d1;
    const float4* Wt24  = (const float4*)W_t2;
    const float* wv1 = w_att1 + HH;
    const float* wv2 = w_att2 + HH;

    void* args[] = { (void*)&text4, (void*)&dns4, (void*)&Wd14, (void*)&Wt24,
                     (void*)&text, (void*)&dns, (void*)&wv1, (void*)&wv2,
                     (void*)&Xb, (void*)&Wb, (void*)&partial, (void*)&out };
    hipLaunchCooperativeKernel((const void*)fused_all, dim3(GRID), dim3(256),
                               args, 0, stream);
}

// Round 20
// 28.452 us; speedup vs baseline: 12.4096x; 12.4096x over previous
//
#include <hip/hip_runtime.h>
#include <hip/hip_bf16.h>
#include <math.h>

#define HH 768
#define NB 8
#define LL 256
#define MM 128
#define NROW1 (NB*MM)        // 1024 dns rows
#define NROW2 (NB*LL)        // 2048 text rows
#define NROWS (NROW1+NROW2)  // 3072
#define NCB 12               // 768/64 column blocks

typedef __attribute__((ext_vector_type(8))) short  bf16x8;
typedef __attribute__((ext_vector_type(4))) float  f32x4;

static __device__ __forceinline__ unsigned int pkbf2(float a, float b) {
    __hip_bfloat162 h = __float22bfloat162_rn(make_float2(a, b));
    unsigned int u; __builtin_memcpy(&u, &h, 4); return u;
}

static __device__ __forceinline__ float fast_tanh(float x) {
    float e = __expf(2.0f * x);
    return 1.0f - 2.0f * __builtin_amdgcn_rcpf(e + 1.0f);
}

// async global->LDS DMA, 16B per lane (r13/r14-proven).
static __device__ __forceinline__ void gload_lds16(const void* g, void* l) {
    __builtin_amdgcn_global_load_lds(
        (const __attribute__((address_space(1))) unsigned int*)g,
        (__attribute__((address_space(3))) unsigned int*)l, 16, 0, 0);
}

// ---------------------------------------------------------------------------
// One-shot fp32 -> bf16 conversion of all GEMM operands. (proven r4-r18)
// ---------------------------------------------------------------------------
__global__ __launch_bounds__(256) void prep_bf16(
    const float4* __restrict__ text, const float4* __restrict__ dns,
    const float4* __restrict__ Wd1, const float4* __restrict__ Wt2,
    uint2* __restrict__ Xb, uint2* __restrict__ Wb)
{
    const int i = blockIdx.x * 256 + threadIdx.x;   // 884736 threads exactly
    const float4* src; uint2* dst;
    if (i < 589824) {
        dst = Xb + i;
        src = (i < 196608) ? (dns + i) : (text + (i - 196608));
    } else {
        dst = Wb + (i - 589824);
        src = (i < 737280) ? (Wd1 + (i - 589824)) : (Wt2 + (i - 737280));
    }
    float4 v = *src;
    uint2 o; o.x = pkbf2(v.x, v.y); o.y = pkbf2(v.z, v.w);
    *dst = o;
}

// ---------------------------------------------------------------------------
// Score GEMM (verbatim r14 -- measured optimum, 28.3 us total):
// gload_lds16 staging with source-XOR swizzle (conflict-free b128 reads,
// rule #21 both-sides swizzle), TRIPLE-buffered LDS, ONE s_barrier/iter,
// counted s_waitcnt vmcnt(4) so the next tile's 4 DMAs stay in flight
// across the barrier (T3/T4-mini); only the last iter drains to 0.
// 576 blocks x 4 waves, 64x64 tile, BK=64, XCD-chunked bijective swizzle.
// ---------------------------------------------------------------------------
__global__ __launch_bounds__(256) void score_mfma(
    const unsigned short* __restrict__ Xb, const unsigned short* __restrict__ Wb,
    const float* __restrict__ wv1, const float* __restrict__ wv2,
    float* __restrict__ partial)
{
    __shared__ __align__(16) unsigned short A3[3][64 * 64];   // 24 KB
    __shared__ __align__(16) unsigned short B3[3][64 * 64];   // 24 KB

    const int t = threadIdx.x;
    const int tile = (blockIdx.x >> 3) + (blockIdx.x & 7) * 72;  // 576 = 8*72
    const int rb = tile / 12, cb = tile % 12;
    const int row0 = rb * 64, col0 = cb * 64;

    const unsigned short* X = Xb + (size_t)row0 * HH;
    const unsigned short* W; const float* wv;
    if (row0 < NROW1) { W = Wb;                    wv = wv1; }
    else              { W = Wb + (size_t)HH * HH;  wv = wv2; }

    const int l  = t & 63;
    const int w  = t >> 6;
    const int wr = w * 16;        // this wave's 16 output rows
    const int lc = l & 15;

    // staging geometry (verbatim r13): lane i stages row w*16 + (i>>3),
    // stored chunk i&7, global chunk (i&7)^(i>>3).
    const int roff = l >> 3;                    // 0..7
    const int gch  = ((l & 7) ^ roff) * 8;      // swizzled global k offset
    const int rA0  = w * 16 + roff;
    const unsigned short* apx = X + (size_t)rA0 * HH + gch;
    const unsigned short* bpx = W + (size_t)(col0 + rA0) * HH + gch;

    f32x4 acc[4] = {};

    auto STAGE = [&](int buf, int k0) {
        unsigned short* Abase = &A3[buf][(w * 16) * 64];
        unsigned short* Bbase = &B3[buf][(w * 16) * 64];
        gload_lds16(apx + k0,            Abase);
        gload_lds16(apx + 8 * HH + k0,   Abase + 8 * 64);
        gload_lds16(bpx + k0,            Bbase);
        gload_lds16(bpx + 8 * HH + k0,   Bbase + 8 * 64);
    };

    auto MFMA_TILE = [&](int buf) {
        #pragma unroll
        for (int kk = 0; kk < 2; ++kk) {
            const int C = kk * 4 + (l >> 4);                 // k-chunk 0..7
            const int sw = (C ^ (lc & 7)) * 8;               // swizzled chunk
            bf16x8 a = *reinterpret_cast<const bf16x8*>(&A3[buf][(wr + lc) * 64 + sw]);
            #pragma unroll
            for (int n = 0; n < 4; ++n) {
                bf16x8 b = *reinterpret_cast<const bf16x8*>(&B3[buf][(n * 16 + lc) * 64 + sw]);
                acc[n] = __builtin_amdgcn_mfma_f32_16x16x32_bf16(a, b, acc[n], 0, 0, 0);
            }
        }
    };

    // prologue: tiles 0,1 in flight (8 DMAs/wave outstanding)
    STAGE(0, 0);
    STAGE(1, 64);

    #pragma unroll 1
    for (int k = 0; k < 12; ++k) {
        if (k < 11) asm volatile("s_waitcnt vmcnt(4)" ::: "memory");
        else        asm volatile("s_waitcnt vmcnt(0)" ::: "memory");
        __builtin_amdgcn_s_barrier();         // tile k landed in all waves
        MFMA_TILE(k % 3);
        __builtin_amdgcn_sched_barrier(0);    // pin reads before next DMAs
        if (k < 10) STAGE((k + 2) % 3, (k + 2) * 64);
    }

    // epilogue (verbatim r7): tanh * wvec over 64 cols, 16-lane reduce
    float wvn[4];
    #pragma unroll
    for (int n = 0; n < 4; ++n) wvn[n] = wv[col0 + n*16 + lc];
    #pragma unroll
    for (int i = 0; i < 4; ++i) {
        float s = 0.f;
        #pragma unroll
        for (int n = 0; n < 4; ++n) s += fast_tanh(acc[n][i]) * wvn[n];
        s += __shfl_xor(s, 1);
        s += __shfl_xor(s, 2);
        s += __shfl_xor(s, 4);
        s += __shfl_xor(s, 8);
        if (lc == 0)
            partial[(size_t)(row0 + wr + (l >> 4)*4 + i) * NCB + cb] = s;
    }
}

// ---------------------------------------------------------------------------
// Fused tail (verbatim r7/r14): softmax from L2-hot partials + weighted sums
// + broadcast write. Grid (8, 48), 256 threads.
// ---------------------------------------------------------------------------
__global__ __launch_bounds__(256) void tail_kernel(
    const float* __restrict__ text, const float* __restrict__ dns,
    const float* __restrict__ partial, float* __restrict__ out)
{
    const int b = blockIdx.x, hc = blockIdx.y;   // hc 0..47
    const int t = threadIdx.x;
    __shared__ float p1s[128], p2s[256], red[8];
    __shared__ __align__(16) float bt[256], bd[256];

    if (t < 128) {
        const float* pr = partial + (size_t)(b * MM + t) * NCB;
        float s = 0.f;
        #pragma unroll
        for (int c = 0; c < NCB; ++c) s += pr[c];
        p1s[t] = s;
    }
    {
        const float* pr = partial + (size_t)(NROW1 + b * LL + t) * NCB;
        float s = 0.f;
        #pragma unroll
        for (int c = 0; c < NCB; ++c) s += pr[c];
        p2s[t] = s;
    }
    __syncthreads();

    float x1 = (t < 128) ? p1s[t] : -1e30f;
    float m1 = x1;
    #pragma unroll
    for (int d = 1; d < 64; d <<= 1) m1 = fmaxf(m1, __shfl_xor(m1, d));
    if ((t & 63) == 0) red[t >> 6] = m1;
    float x2 = p2s[t];
    float m2 = x2;
    #pragma unroll
    for (int d = 1; d < 64; d <<= 1) m2 = fmaxf(m2, __shfl_xor(m2, d));
    if ((t & 63) == 0) red[4 + (t >> 6)] = m2;
    __syncthreads();
    m1 = fmaxf(fmaxf(red[0], red[1]), fmaxf(red[2], red[3]));
    m2 = fmaxf(fmaxf(red[4], red[5]), fmaxf(red[6], red[7]));

    float e1 = (t < 128) ? __expf(x1 - m1) : 0.f;
    float e2 = __expf(x2 - m2);
    __syncthreads();
    float s1 = e1, s2 = e2;
    #pragma unroll
    for (int d = 1; d < 64; d <<= 1) { s1 += __shfl_xor(s1, d); s2 += __shfl_xor(s2, d); }
    if ((t & 63) == 0) { red[t >> 6] = s1; red[4 + (t >> 6)] = s2; }
    __syncthreads();
    s1 = red[0] + red[1] + red[2] + red[3];
    s2 = red[4] + red[5] + red[6] + red[7];
    if (t < 128) p1s[t] = e1 / s1;
    p2s[t] = e2 / s2;
    __syncthreads();

    const int hh  = hc * 16 + (t & 15);
    const int rsl = t >> 4;                      // 0..15 row-slices

    const int jr0 = rsl * 16;                    // 16 text rows per slice
    float st = 0.f;
    #pragma unroll
    for (int r = 0; r < 16; ++r)
        st = fmaf(p2s[jr0 + r], text[(size_t)(b * LL + jr0 + r) * HH + hh], st);

    const int mr0 = rsl * 8;                     // 8 dns rows per slice
    float sd = 0.f;
    #pragma unroll
    for (int r = 0; r < 8; ++r)
        sd = fmaf(p1s[mr0 + r], dns[(size_t)(b * MM + mr0 + r) * HH + hh], sd);

    bt[t] = st; bd[t] = sd;
    __syncthreads();
    if (t < 128) { bt[t] += bt[t + 128]; bd[t] += bd[t + 128]; } __syncthreads();
    if (t < 64)  { bt[t] += bt[t + 64];  bd[t] += bd[t + 64];  } __syncthreads();
    if (t < 32)  { bt[t] += bt[t + 32];  bd[t] += bd[t + 32];  } __syncthreads();
    if (t < 16)  { bt[t] += bt[t + 16];  bd[t] += bd[t + 16];  }
    __syncthreads();

    const int H4 = HH / 4;                       // 192
    const int n4out = NB * LL * H4;              // 393216
    const float4* svt4 = reinterpret_cast<const float4*>(bt);
    const float4* svd4 = reinterpret_cast<const float4*>(bd);
    float4* out4 = reinterpret_cast<float4*>(out);
    #pragma unroll
    for (int i = t; i < LL * 4; i += 256) {      // 1024 = 256 rows x 4 f4
        const int ll = i >> 2, c4 = i & 3;
        const size_t o = (size_t)(b * LL + ll) * H4 + hc * 4 + c4;
        out4[o] = svt4[c4];
        out4[n4out + o] = svd4[c4];
    }
}

extern "C" void kernel_launch(void* const* d_in, const int* in_sizes, int n_in,
                              void* d_out, int out_size, void* d_ws, size_t ws_size,
                              hipStream_t stream) {
    const float* text   = (const float*)d_in[0];   // (8,256,768)
    const float* dns    = (const float*)d_in[1];   // (8,128,768)
    const float* W_d1   = (const float*)d_in[4];   // (768,768)
    const float* w_att1 = (const float*)d_in[5];   // (1536,)
    const float* W_t2   = (const float*)d_in[9];   // (768,768)
    const float* w_att2 = (const float*)d_in[10];  // (1536,)

    float* ws      = (float*)d_ws;
    float* partial = ws;                                   // 36864 f
    unsigned short* Xb = (unsigned short*)(ws + 36864);    // 2359296 bf16
    unsigned short* Wb = Xb + (size_t)NROWS * HH;          // 1179648 bf16
    float* out     = (float*)d_out;

    prep_bf16<<<3456, 256, 0, stream>>>(
        (const float4*)text, (const float4*)dns, (const float4*)W_d1,
        (const float4*)W_t2, (uint2*)Xb, (uint2*)Wb);
    score_mfma<<<576, 256, 0, stream>>>(
        Xb, Wb, w_att1 + HH, w_att2 + HH, partial);
    tail_kernel<<<dim3(NB, 48), 256, 0, stream>>>(text, dns, partial, out);
}